// Round 1
// baseline (129.790 us; speedup 1.0000x reference)
//
#include <hip/hip_runtime.h>

// Problem constants
#define B_SIZE 16384
#define D_DIM  1024
#define T_DIM  128
#define VLn    12
#define SLSTR  132            // per-row LDS stride in floats (128 + 4 pad)

typedef _Float16 half8  __attribute__((ext_vector_type(8)));
typedef __fp16   fp16x2 __attribute__((ext_vector_type(2)));
typedef float    f32x4  __attribute__((ext_vector_type(4)));

union Pack16 { fp16x2 h[4]; uint4 u; half8 v; };
union Frag   { uint4 u; half8 h; };

__device__ __forceinline__ uint4 pack8u(float4 v0, float4 v1) {
    Pack16 un;
    un.h[0] = __builtin_amdgcn_cvt_pkrtz(v0.x, v0.y);
    un.h[1] = __builtin_amdgcn_cvt_pkrtz(v0.z, v0.w);
    un.h[2] = __builtin_amdgcn_cvt_pkrtz(v1.x, v1.y);
    un.h[3] = __builtin_amdgcn_cvt_pkrtz(v1.z, v1.w);
    return un.u;
}
// f16 A-frag from two float4 (identical numerics to previous version)
__device__ __forceinline__ half8 mk8(float4 v0, float4 v1) {
    Pack16 un;
    un.h[0] = __builtin_amdgcn_cvt_pkrtz(v0.x, v0.y);
    un.h[1] = __builtin_amdgcn_cvt_pkrtz(v0.z, v0.w);
    un.h[2] = __builtin_amdgcn_cvt_pkrtz(v1.x, v1.y);
    un.h[3] = __builtin_amdgcn_cvt_pkrtz(v1.z, v1.w);
    return un.v;
}

// W fp32 [128][1024] -> f16, swizzled into MFMA B-fragment order (verified):
// unit j: kcW=j>>10, g=(j&1023)>>6, lane=j&63;
// holds W[n = (g&7)*16 + (lane&15)][k = kcW*64 + (g>>3)*32 + (lane>>4)*8 .. +8].
// Also zeroes the output accumulator (replaces the hipMemsetAsync dispatch;
// conv_w completes before qloss starts via stream order).
__global__ __launch_bounds__(256)
void conv_w(const float* __restrict__ W, uint4* __restrict__ Wf,
            float* __restrict__ out) {
    if (blockIdx.x == 0 && threadIdx.x == 0) out[0] = 0.0f;
    const int j    = blockIdx.x * 256 + threadIdx.x;   // 0..16383
    const int kc   = j >> 10;
    const int r    = j & 1023;
    const int g    = r >> 6;
    const int lane = r & 63;
    const int n = (g & 7) * 16 + (lane & 15);
    const int k = kc * 64 + (g >> 3) * 32 + ((lane >> 4) << 3);
    const float* src = W + (size_t)n * D_DIM + k;
    Wf[j] = pack8u(*(const float4*)src, *(const float4*)(src + 4));
}

// 256 blocks x 256 threads (4 waves). Each WAVE independently owns a 16-row
// tile (r0 = blockIdx*64 + w*16) and all 128 output columns:
//   acc[ct] (ct=0..7) is the 16x16 MFMA C-tile for cols ct*16..ct*16+15.
// A-frags are built DIRECTLY from global memory (lane reads 2x float4 of its
// own row: A[row=lane&15][k = s*32 + (lane>>4)*8 .. +8]) — no LDS staging,
// no __syncthreads anywhere. One-iteration register prefetch (bc/bn + a*n)
// keeps ~10 KB/wave of loads in flight; the compiler emits counted vmcnt
// (no barrier => no vmcnt(0) drain), so HBM stays saturated.
// B-frags stream from the pre-swizzled L2-resident Wf: Wf[s*512 + ct*64 + lane].
// Softmax + gather are wave-local (row r is held by the 16-lane group
// quad = r>>2; probs staged in a per-wave-private LDS region, same-wave
// lgkmcnt ordering only).
__global__ __launch_bounds__(256, 1)
void qloss_kernel(const float* __restrict__ emb,
                  const uint4* __restrict__ Wf,
                  const float* __restrict__ bias,
                  const int*   __restrict__ didx,
                  const int*   __restrict__ dmsk,
                  float*       __restrict__ out)
{
    __shared__ float sP[4][16 * SLSTR];   // 4 waves x 16 rows x 132 = 33792 B

    const int t    = threadIdx.x;
    const int w    = t >> 6;
    const int lane = t & 63;
    const int m15  = lane & 15;
    const int quad = lane >> 4;
    const int r0   = blockIdx.x * 64 + w * 16;   // wave's first row

    const float* aP = emb + (size_t)(r0 + m15) * D_DIM + quad * 8;
    const uint4* bQ = Wf + lane;

    f32x4 acc[8];
#pragma unroll
    for (int ct = 0; ct < 8; ++ct) acc[ct] = (f32x4){0.f, 0.f, 0.f, 0.f};

    Frag bc[8], bn[8];
    float4 a0c, a1c, a0n, a1n;

    // prologue: k-step 0
    a0c = *(const float4*)(aP);
    a1c = *(const float4*)(aP + 4);
#pragma unroll
    for (int ct = 0; ct < 8; ++ct) bc[ct].u = bQ[ct * 64];

#pragma unroll 2
    for (int s = 0; s < 32; ++s) {
        if (s + 1 < 32) {
            a0n = *(const float4*)(aP + (s + 1) * 32);
            a1n = *(const float4*)(aP + (s + 1) * 32 + 4);
#pragma unroll
            for (int ct = 0; ct < 8; ++ct)
                bn[ct].u = bQ[(s + 1) * 512 + ct * 64];
        }
        const half8 a = mk8(a0c, a1c);
#pragma unroll
        for (int ct = 0; ct < 8; ++ct)
            acc[ct] = __builtin_amdgcn_mfma_f32_16x16x32_f16(a, bc[ct].h, acc[ct], 0, 0, 0);
        a0c = a0n; a1c = a1n;
#pragma unroll
        for (int ct = 0; ct < 8; ++ct) bc[ct] = bn[ct];
    }

    // ---- epilogue (wave-local, no barriers) ----
    // C layout (verified): acc[ct][i] = C[row = quad*4 + i][col = ct*16 + m15]
    float bv[8];
#pragma unroll
    for (int ct = 0; ct < 8; ++ct) bv[ct] = bias[ct * 16 + m15];

#pragma unroll
    for (int i = 0; i < 4; ++i) {
        const int row = quad * 4 + i;
        float mx = -1e30f;
#pragma unroll
        for (int ct = 0; ct < 8; ++ct) {
            acc[ct][i] += bv[ct];
            mx = fmaxf(mx, acc[ct][i]);
        }
#pragma unroll
        for (int off = 1; off < 16; off <<= 1) mx = fmaxf(mx, __shfl_xor(mx, off));
        float ss = 0.f;
#pragma unroll
        for (int ct = 0; ct < 8; ++ct) {
            const float e = __expf(acc[ct][i] - mx);
            acc[ct][i] = e;
            ss += e;
        }
#pragma unroll
        for (int off = 1; off < 16; off <<= 1) ss += __shfl_xor(ss, off);
        const float inv = 1.0f / ss;
#pragma unroll
        for (int ct = 0; ct < 8; ++ct)
            sP[w][row * SLSTR + ct * 16 + m15] = acc[ct][i] * inv;
    }

    // gather: 16 rows x 12 labels = 192 items = 3 x 64 lanes (exact)
    float p = 0.f;
#pragma unroll
    for (int e = 0; e < 3; ++e) {
        const int item = e * 64 + lane;
        const int row  = item / VLn;
        const int j    = item - row * VLn;
        const int gi   = (r0 + row) * VLn + j;
        const int mk   = dmsk[gi];
        const int idx  = didx[gi];
        if (mk) p += sP[w][row * SLSTR + idx];
    }
#pragma unroll
    for (int off = 1; off < 64; off <<= 1) p += __shfl_xor(p, off);
    if (lane == 0) atomicAdd(out, p * (1.0f / 65536.0f));
}

extern "C" void kernel_launch(void* const* d_in, const int* in_sizes, int n_in,
                              void* d_out, int out_size, void* d_ws, size_t ws_size,
                              hipStream_t stream) {
    const float* emb  = (const float*)d_in[0];
    const float* W    = (const float*)d_in[1];
    const float* bias = (const float*)d_in[2];
    const int*   didx = (const int*)d_in[3];
    const int*   dmsk = (const int*)d_in[4];
    float* out = (float*)d_out;

    uint4* Wf = (uint4*)d_ws;   // 256 KB swizzled f16 W

    conv_w<<<64, 256, 0, stream>>>(W, Wf, out);
    qloss_kernel<<<B_SIZE / 64, 256, 0, stream>>>(emb, Wf, bias, didx, dmsk, out);
}

// Round 2
// 112.959 us; speedup vs baseline: 1.1490x; 1.1490x over previous
//
#include <hip/hip_runtime.h>

// Problem constants
#define B_SIZE 16384
#define D_DIM  1024
#define T_DIM  128
#define VLn    12
#define BM     16              // rows per block (one m-tile)
#define BK     256             // K per chunk -> 1 KB per row per chunk (linear DMA)
#define NCHUNK 4
#define GRID   (B_SIZE / BM)   // 1024
#define AROWF  258             // LDS A row stride in floats (256 + 2 pad -> 4-way banks)
#define AROWB  1032            // bytes
#define ABUFB  (BM * AROWB)    // 16512 B per buffer
#define SLSTR  132

typedef _Float16 half8  __attribute__((ext_vector_type(8)));
typedef __fp16   fp16x2 __attribute__((ext_vector_type(2)));
typedef float    f32x4  __attribute__((ext_vector_type(4)));

union Pack16 { fp16x2 h[4]; uint4 u; half8 v; };
union Frag   { uint4 u; half8 h; };

__device__ __forceinline__ uint4 pack8u(float4 v0, float4 v1) {
    Pack16 un;
    un.h[0] = __builtin_amdgcn_cvt_pkrtz(v0.x, v0.y);
    un.h[1] = __builtin_amdgcn_cvt_pkrtz(v0.z, v0.w);
    un.h[2] = __builtin_amdgcn_cvt_pkrtz(v1.x, v1.y);
    un.h[3] = __builtin_amdgcn_cvt_pkrtz(v1.z, v1.w);
    return un.u;
}
// build f16 A-frag from 8 consecutive f32 in LDS (8-B aligned)
__device__ __forceinline__ half8 pack8f(const float* fp) {
    const float2 a = ((const float2*)fp)[0];
    const float2 b = ((const float2*)fp)[1];
    const float2 c = ((const float2*)fp)[2];
    const float2 d = ((const float2*)fp)[3];
    Pack16 un;
    un.h[0] = __builtin_amdgcn_cvt_pkrtz(a.x, a.y);
    un.h[1] = __builtin_amdgcn_cvt_pkrtz(b.x, b.y);
    un.h[2] = __builtin_amdgcn_cvt_pkrtz(c.x, c.y);
    un.h[3] = __builtin_amdgcn_cvt_pkrtz(d.x, d.y);
    return un.v;
}

// async global->LDS DMA, 16 B/lane: LDS dest = wave-uniform base + lane*16
__device__ __forceinline__ void dma16(const float* g, void* l) {
    __builtin_amdgcn_global_load_lds(
        (__attribute__((address_space(1))) void*)g,
        (__attribute__((address_space(3))) void*)l, 16, 0, 0);
}

// W fp32 [128][1024] -> f16, swizzled into MFMA B-fragment order (verified):
// unit j: kcW=j>>10, g=(j&1023)>>6 (g = ksW*8+CT), lane=j&63;
// holds W[n = CT*16 + (lane&15)][k = kcW*64 + ksW*32 + (lane>>4)*8 .. +8].
// Also zeroes the scalar output (replaces the hipMemsetAsync dispatch).
__global__ __launch_bounds__(256)
void conv_w(const float* __restrict__ W, uint4* __restrict__ Wf,
            float* __restrict__ out) {
    if (blockIdx.x == 0 && threadIdx.x == 0) out[0] = 0.0f;
    const int j    = blockIdx.x * 256 + threadIdx.x;   // 0..16383
    const int kc   = j >> 10;
    const int r    = j & 1023;
    const int g    = r >> 6;
    const int lane = r & 63;
    const int n = (g & 7) * 16 + (lane & 15);
    const int k = kc * 64 + (g >> 3) * 32 + ((lane >> 4) << 3);
    const float* src = W + (size_t)n * D_DIM + k;
    Wf[j] = pack8u(*(const float4*)src, *(const float4*)(src + 4));
}

// 1024 blocks x 256 threads (4 waves), 2 blocks/CU. Block = 16 rows x 128
// cols x full K. Wave w owns col-tiles {2w, 2w+1}.
// A: async DMA (global_load_lds width 16) into double-buffered LDS.
// B: register prefetch (1 chunk ahead) from pre-swizzled Wf.
// KEY CHANGE vs the 114-us version: the per-chunk __syncthreads() (which
// lowers to s_waitcnt vmcnt(0) — a FULL drain of the just-issued next-chunk
// DMA + B loads, every chunk) is replaced by a counted wait + raw barrier:
//   [DMA(kc+1) x4][B(kc+1) x16][compute kc][s_waitcnt vmcnt(16)][s_barrier]
// vmcnt retires in order, so vmcnt(16) waits ONLY the 4 oldest ops (this
// wave's DMA — required before other waves read the LDS buffer), while the
// 16 newer B loads stay in flight across the barrier. Nothing in the main
// loop ever drains vmcnt to 0, so the HBM pipe keeps >=16 KB/CU outstanding
// continuously. bc-use waits inside compute are compiler-counted (the bc
// frags are the oldest outstanding ops at that point).
__global__ __launch_bounds__(256, 2)
void qloss_kernel(const float* __restrict__ emb,
                  const uint4* __restrict__ Wf,
                  const float* __restrict__ bias,
                  const int*   __restrict__ didx,
                  const int*   __restrict__ dmsk,
                  float*       __restrict__ out)
{
    __shared__ __align__(16) unsigned char smem[2 * ABUFB + 16];   // 33040 B
    float* sL   = (float*)smem;                    // [16][132] epilogue alias
    float* sRed = (float*)(smem + 2 * ABUFB);

    const int t    = threadIdx.x;
    const int w    = t >> 6;
    const int lane = t & 63;
    const int m15  = lane & 15;
    const int quad = lane >> 4;
    const int r0   = blockIdx.x * BM;

    // DMA: wave w stages rows 4w..4w+3; per row one call (64 lanes x 16 B = 1 KB)
    const float* aG0 = emb + (size_t)(r0 + 4 * w) * D_DIM + lane * 4;

    // B frag for global k-step s (32 k each), col-tile ct:
    //   Wf[(s>>1)*1024 + ((s&1)*8 + ct)*64 + lane]
    const uint4* bP = Wf + lane;
    const int CT0 = 2 * w;

    f32x4 acc[2];
    acc[0] = (f32x4){0.f, 0.f, 0.f, 0.f};
    acc[1] = (f32x4){0.f, 0.f, 0.f, 0.f};

    Frag bc[16], bn[16];

    // ---- prologue: DMA chunk 0 -> buf0 (oldest), then B(chunk 0) -> bc ----
#pragma unroll
    for (int r = 0; r < 4; ++r)
        dma16(aG0 + (size_t)r * D_DIM, smem + (4 * w + r) * AROWB);
#pragma unroll
    for (int ks = 0; ks < 8; ++ks) {
        const int s = ks;                     // chunk 0
#pragma unroll
        for (int j = 0; j < 2; ++j)
            bc[ks * 2 + j].u = bP[(size_t)(s >> 1) * 1024 + ((s & 1) * 8 + CT0 + j) * 64];
    }
    // own DMA (4 oldest ops) done; bc loads (16 newer) may remain in flight
    asm volatile("s_waitcnt vmcnt(16)" ::: "memory");
    __builtin_amdgcn_sched_barrier(0);
    __builtin_amdgcn_s_barrier();
    __builtin_amdgcn_sched_barrier(0);

#pragma unroll
    for (int kc = 0; kc < NCHUNK; ++kc) {
        const unsigned char* bufC = smem + (kc & 1) * ABUFB;
        unsigned char*       bufN = (unsigned char*)smem + ((kc & 1) ^ 1) * ABUFB;

        // issue next chunk's DMA first (oldest), then B loads (newer) —
        // order matters: the counted wait below retires only the DMA.
        if (kc + 1 < NCHUNK) {
#pragma unroll
            for (int r = 0; r < 4; ++r)
                dma16(aG0 + (size_t)r * D_DIM + (kc + 1) * BK,
                      bufN + (4 * w + r) * AROWB);
#pragma unroll
            for (int ks = 0; ks < 8; ++ks) {
                const int s = (kc + 1) * 8 + ks;
#pragma unroll
                for (int j = 0; j < 2; ++j)
                    bn[ks * 2 + j].u =
                        bP[(size_t)(s >> 1) * 1024 + ((s & 1) * 8 + CT0 + j) * 64];
            }
        }

        // compute chunk kc: 8 k-steps x 2 col-tiles
#pragma unroll
        for (int ks = 0; ks < 8; ++ks) {
            const float* fp = (const float*)bufC + m15 * AROWF + ks * 32 + quad * 8;
            const half8 a = pack8f(fp);
            acc[0] = __builtin_amdgcn_mfma_f32_16x16x32_f16(a, bc[ks * 2 + 0].h, acc[0], 0, 0, 0);
            acc[1] = __builtin_amdgcn_mfma_f32_16x16x32_f16(a, bc[ks * 2 + 1].h, acc[1], 0, 0, 0);
        }

        if (kc + 1 < NCHUNK) {
            // wait own DMA(kc+1) (the 4 oldest outstanding VMEM ops) before
            // signaling; B(kc+1) stays in flight across the barrier.
            asm volatile("s_waitcnt vmcnt(16)" ::: "memory");
            __builtin_amdgcn_sched_barrier(0);
            __builtin_amdgcn_s_barrier();
            __builtin_amdgcn_sched_barrier(0);
#pragma unroll
            for (int q = 0; q < 16; ++q) bc[q] = bn[q];
        }
    }

    // ---- epilogue: logits -> sL (aliases buf0; all A-reads done) ----
    __syncthreads();   // full drain is harmless here (nothing critical in flight)
    const float b0v = bias[CT0 * 16 + m15];
    const float b1v = bias[(CT0 + 1) * 16 + m15];
#pragma unroll
    for (int i = 0; i < 4; ++i) {
        const int row = quad * 4 + i;
        sL[row * SLSTR + CT0 * 16 + m15]       = acc[0][i] + b0v;
        sL[row * SLSTR + (CT0 + 1) * 16 + m15] = acc[1][i] + b1v;
    }
    __syncthreads();

    // softmax: 16 threads/row, 8 cols each (xor 1,2,4,8 stays in 16-group)
    {
        const int row = t >> 4, s = t & 15;
        float* base = &sL[row * SLSTR + s * 8];
        float v[8];
        *(float4*)&v[0] = *(const float4*)(base);
        *(float4*)&v[4] = *(const float4*)(base + 4);
        float m = -1e30f;
#pragma unroll
        for (int j = 0; j < 8; ++j) m = fmaxf(m, v[j]);
#pragma unroll
        for (int off = 1; off < 16; off <<= 1) m = fmaxf(m, __shfl_xor(m, off));
        float ssum = 0.f;
#pragma unroll
        for (int j = 0; j < 8; ++j) { v[j] = __expf(v[j] - m); ssum += v[j]; }
#pragma unroll
        for (int off = 1; off < 16; off <<= 1) ssum += __shfl_xor(ssum, off);
        const float inv = 1.0f / ssum;
#pragma unroll
        for (int j = 0; j < 8; ++j) v[j] *= inv;
        *(float4*)(base)     = *(const float4*)&v[0];
        *(float4*)(base + 4) = *(const float4*)&v[4];
    }
    __syncthreads();

    // gather: 192 (row, j) entries; block partial -> one atomicAdd
    float p = 0.f;
    if (t < BM * VLn) {
        const int gi  = r0 * VLn + t;
        const int row = t / VLn;
        const int idx = didx[gi];
        const int mk  = dmsk[gi];
        p = mk ? sL[row * SLSTR + idx] : 0.f;
    }
#pragma unroll
    for (int off = 1; off < 64; off <<= 1) p += __shfl_xor(p, off);
    if (lane == 0) sRed[w] = p;
    __syncthreads();
    if (t == 0)
        atomicAdd(out, (sRed[0] + sRed[1] + sRed[2] + sRed[3]) * (1.0f / 65536.0f));
}

extern "C" void kernel_launch(void* const* d_in, const int* in_sizes, int n_in,
                              void* d_out, int out_size, void* d_ws, size_t ws_size,
                              hipStream_t stream) {
    const float* emb  = (const float*)d_in[0];
    const float* W    = (const float*)d_in[1];
    const float* bias = (const float*)d_in[2];
    const int*   didx = (const int*)d_in[3];
    const int*   dmsk = (const int*)d_in[4];
    float* out = (float*)d_out;

    uint4* Wf = (uint4*)d_ws;   // 256 KB swizzled f16 W

    conv_w<<<64, 256, 0, stream>>>(W, Wf, out);
    qloss_kernel<<<GRID, 256, 0, stream>>>(emb, Wf, bias, didx, dmsk, out);
}

// Round 4
// 112.028 us; speedup vs baseline: 1.1586x; 1.0083x over previous
//
#include <hip/hip_runtime.h>

// Problem constants
#define B_SIZE 16384
#define D_DIM  1024
#define T_DIM  128
#define VLn    12
#define BM     32              // rows per block
#define BK     256             // K per chunk -> 1 KB per row per chunk (linear DMA)
#define NCHUNK 4
#define NTHR   512             // 8 waves
#define GRID   (B_SIZE / BM)   // 512
#define AROWF  258             // LDS A row stride in floats (256 + 2 pad -> 4-way banks)
#define AROWB  1032            // bytes
#define ABUFB  (BM * AROWB)    // 33024 B per buffer
#define SLSTR  132

typedef _Float16 half8  __attribute__((ext_vector_type(8)));
typedef __fp16   fp16x2 __attribute__((ext_vector_type(2)));
typedef float    f32x4  __attribute__((ext_vector_type(4)));

union Pack16 { fp16x2 h[4]; uint4 u; half8 v; };
union Frag   { uint4 u; half8 h; };

__device__ __forceinline__ uint4 pack8u(float4 v0, float4 v1) {
    Pack16 un;
    un.h[0] = __builtin_amdgcn_cvt_pkrtz(v0.x, v0.y);
    un.h[1] = __builtin_amdgcn_cvt_pkrtz(v0.z, v0.w);
    un.h[2] = __builtin_amdgcn_cvt_pkrtz(v1.x, v1.y);
    un.h[3] = __builtin_amdgcn_cvt_pkrtz(v1.z, v1.w);
    return un.u;
}
// build f16 A-frag from 8 consecutive f32 in LDS (8-B aligned)
__device__ __forceinline__ half8 pack8f(const float* fp) {
    const float2 a = ((const float2*)fp)[0];
    const float2 b = ((const float2*)fp)[1];
    const float2 c = ((const float2*)fp)[2];
    const float2 d = ((const float2*)fp)[3];
    Pack16 un;
    un.h[0] = __builtin_amdgcn_cvt_pkrtz(a.x, a.y);
    un.h[1] = __builtin_amdgcn_cvt_pkrtz(b.x, b.y);
    un.h[2] = __builtin_amdgcn_cvt_pkrtz(c.x, c.y);
    un.h[3] = __builtin_amdgcn_cvt_pkrtz(d.x, d.y);
    return un.v;
}

// async global->LDS DMA, 16 B/lane: LDS dest = wave-uniform base + lane*16
__device__ __forceinline__ void dma16(const float* g, void* l) {
    __builtin_amdgcn_global_load_lds(
        (__attribute__((address_space(1))) void*)g,
        (__attribute__((address_space(3))) void*)l, 16, 0, 0);
}

// W fp32 [128][1024] -> f16, swizzled into MFMA B-fragment order (verified):
// unit j: kcW=j>>10, g=(j&1023)>>6 (g = ksW*8+CT), lane=j&63;
// holds W[n = CT*16 + (lane&15)][k = kcW*64 + ksW*32 + (lane>>4)*8 .. +8].
// Also zeroes the scalar output (replaces the hipMemsetAsync dispatch).
__global__ __launch_bounds__(256)
void conv_w(const float* __restrict__ W, uint4* __restrict__ Wf,
            float* __restrict__ out) {
    if (blockIdx.x == 0 && threadIdx.x == 0) out[0] = 0.0f;
    const int j    = blockIdx.x * 256 + threadIdx.x;   // 0..16383
    const int kc   = j >> 10;
    const int r    = j & 1023;
    const int g    = r >> 6;
    const int lane = r & 63;
    const int n = (g & 7) * 16 + (lane & 15);
    const int k = kc * 64 + (g >> 3) * 32 + ((lane >> 4) << 3);
    const float* src = W + (size_t)n * D_DIM + k;
    Wf[j] = pack8u(*(const float4*)src, *(const float4*)(src + 4));
}

// 512 blocks x 512 threads (8 waves), __launch_bounds__(512,4) -> 2 blocks/CU
// = 16 waves/CU (4/SIMD): 2x the TLP of the 114-us version. Block = 32 rows
// x 128 cols x full K.
//   DMA:     wave w stages rows 4w..4w+3 of each chunk (4 x 1 KB linear).
//   Compute: wave w owns row-group rg=w>>2 (rows 16rg..16rg+15) and col-tiles
//            CT0=2*(w&3), CT0+1.
// B is prefetched DEPTH-2 PER K-STEP into a 3-slot ring (24 VGPR) instead of
// the old chunk-wide bc[16]/bn[16] (128 VGPR) — the old scheme blew the
// 128-VGPR budget and the compiler sank the prefetch loads to their uses,
// serializing L2 latency into every chunk. Live set now ~90 VGPR, so the
// pipeline survives codegen.
// Chunk barrier: s_waitcnt vmcnt(4) (retires this wave's 4 DMAs — in-order
// retirement — while the 2 newest B pairs stay in flight) + raw s_barrier.
// vmcnt never drains to 0 in the main loop.
__global__ __launch_bounds__(NTHR, 4)
void qloss_kernel(const float* __restrict__ emb,
                  const uint4* __restrict__ Wf,
                  const float* __restrict__ bias,
                  const int*   __restrict__ didx,
                  const int*   __restrict__ dmsk,
                  float*       __restrict__ out)
{
    __shared__ __align__(16) unsigned char smem[2 * ABUFB + 64];   // 66112 B
    float* sL   = (float*)smem;                    // [32][132] epilogue alias
    float* sRed = (float*)(smem + 2 * ABUFB);

    const int t    = threadIdx.x;
    const int w    = t >> 6;
    const int lane = t & 63;
    const int m15  = lane & 15;
    const int quad = lane >> 4;
    const int r0   = blockIdx.x * BM;

    // DMA: wave w stages rows 4w..4w+3; per row one call (64 lanes x 16 B = 1 KB)
    const float* aG0 = emb + (size_t)(r0 + 4 * w) * D_DIM + lane * 4;

    // compute assignment
    const int rg  = w >> 2;            // row-group: rows 16rg..16rg+15
    const int CT0 = 2 * (w & 3);       // col-tiles CT0, CT0+1

    // B frag for global k-step s (32 k each), col-tile ct:
    //   Wf[(s>>1)*1024 + ((s&1)*8 + ct)*64 + lane]
    const uint4* bP = Wf + lane;

    f32x4 acc[2];
    acc[0] = (f32x4){0.f, 0.f, 0.f, 0.f};
    acc[1] = (f32x4){0.f, 0.f, 0.f, 0.f};

    Frag bp[3][2];                     // depth-2 per-k-step B ring (24 VGPR)

#define LOADB(s, slot)                                                        \
    do {                                                                      \
        bp[slot][0].u = bP[(size_t)((s) >> 1) * 1024 +                        \
                           (((s) & 1) * 8 + CT0 + 0) * 64];                   \
        bp[slot][1].u = bP[(size_t)((s) >> 1) * 1024 +                        \
                           (((s) & 1) * 8 + CT0 + 1) * 64];                   \
    } while (0)

    // ---- prologue: DMA chunk 0 (oldest), then B pairs s=0,1 ----
#pragma unroll
    for (int r = 0; r < 4; ++r)
        dma16(aG0 + (size_t)r * D_DIM, smem + (4 * w + r) * AROWB);
    LOADB(0, 0);
    LOADB(1, 1);
    // retire the 4 DMAs (oldest); keep the 4 B loads in flight
    asm volatile("s_waitcnt vmcnt(4)" ::: "memory");
    __builtin_amdgcn_sched_barrier(0);
    __builtin_amdgcn_s_barrier();
    __builtin_amdgcn_sched_barrier(0);

#pragma unroll
    for (int kc = 0; kc < NCHUNK; ++kc) {
        const float* bufC = (const float*)(smem + (kc & 1) * ABUFB);
        unsigned char* bufN = (unsigned char*)smem + ((kc & 1) ^ 1) * ABUFB;

        // next chunk's DMA first (oldest in this iteration's vmcnt window)
        if (kc + 1 < NCHUNK) {
#pragma unroll
            for (int r = 0; r < 4; ++r)
                dma16(aG0 + (size_t)r * D_DIM + (kc + 1) * BK,
                      bufN + (4 * w + r) * AROWB);
        }

        // compute chunk kc: 8 k-steps x 2 col-tiles, B ring 2 steps ahead
#pragma unroll
        for (int ks = 0; ks < 8; ++ks) {
            const int s = kc * 8 + ks;
            if (s + 2 < 32) LOADB(s + 2, (s + 2) % 3);
            const float* fp = bufC + (16 * rg + m15) * AROWF + ks * 32 + quad * 8;
            const half8 a = pack8f(fp);
            acc[0] = __builtin_amdgcn_mfma_f32_16x16x32_f16(a, bp[s % 3][0].h, acc[0], 0, 0, 0);
            acc[1] = __builtin_amdgcn_mfma_f32_16x16x32_f16(a, bp[s % 3][1].h, acc[1], 0, 0, 0);
        }

        if (kc + 1 < NCHUNK) {
            // retire DMA(kc+1) (4 oldest outstanding); the 2 unconsumed B
            // pairs (next chunk's s, s+1) stay in flight across the barrier.
            asm volatile("s_waitcnt vmcnt(4)" ::: "memory");
            __builtin_amdgcn_sched_barrier(0);
            __builtin_amdgcn_s_barrier();
            __builtin_amdgcn_sched_barrier(0);
        }
    }
#undef LOADB

    // ---- epilogue: logits -> sL (aliases buf0; all A-reads done) ----
    __syncthreads();   // single full drain, harmless here
    const float b0v = bias[CT0 * 16 + m15];
    const float b1v = bias[(CT0 + 1) * 16 + m15];
#pragma unroll
    for (int i = 0; i < 4; ++i) {
        const int row = 16 * rg + quad * 4 + i;
        sL[row * SLSTR + CT0 * 16 + m15]       = acc[0][i] + b0v;
        sL[row * SLSTR + (CT0 + 1) * 16 + m15] = acc[1][i] + b1v;
    }
    __syncthreads();

    // softmax: 512 threads = 32 rows x 16 threads, 8 cols each
    {
        const int row = t >> 4, s = t & 15;
        float* base = &sL[row * SLSTR + s * 8];
        float v[8];
        *(float4*)&v[0] = *(const float4*)(base);
        *(float4*)&v[4] = *(const float4*)(base + 4);
        float m = -1e30f;
#pragma unroll
        for (int j = 0; j < 8; ++j) m = fmaxf(m, v[j]);
#pragma unroll
        for (int off = 1; off < 16; off <<= 1) m = fmaxf(m, __shfl_xor(m, off));
        float ssum = 0.f;
#pragma unroll
        for (int j = 0; j < 8; ++j) { v[j] = __expf(v[j] - m); ssum += v[j]; }
#pragma unroll
        for (int off = 1; off < 16; off <<= 1) ssum += __shfl_xor(ssum, off);
        const float inv = 1.0f / ssum;
#pragma unroll
        for (int j = 0; j < 8; ++j) v[j] *= inv;
        *(float4*)(base)     = *(const float4*)&v[0];
        *(float4*)(base + 4) = *(const float4*)&v[4];
    }
    __syncthreads();

    // gather: 32 rows x 12 labels = 384 items; block partial -> one atomicAdd
    float p = 0.f;
    if (t < BM * VLn) {
        const int gi  = r0 * VLn + t;
        const int row = t / VLn;
        const int idx = didx[gi];
        const int mk  = dmsk[gi];
        p = mk ? sL[row * SLSTR + idx] : 0.f;
    }
#pragma unroll
    for (int off = 1; off < 64; off <<= 1) p += __shfl_xor(p, off);
    if (lane == 0) sRed[w] = p;
    __syncthreads();
    if (t == 0) {
        float s = 0.f;
#pragma unroll
        for (int i = 0; i < 8; ++i) s += sRed[i];
        atomicAdd(out, s * (1.0f / 65536.0f));
    }
}

extern "C" void kernel_launch(void* const* d_in, const int* in_sizes, int n_in,
                              void* d_out, int out_size, void* d_ws, size_t ws_size,
                              hipStream_t stream) {
    const float* emb  = (const float*)d_in[0];
    const float* W    = (const float*)d_in[1];
    const float* bias = (const float*)d_in[2];
    const int*   didx = (const int*)d_in[3];
    const int*   dmsk = (const int*)d_in[4];
    float* out = (float*)d_out;

    uint4* Wf = (uint4*)d_ws;   // 256 KB swizzled f16 W

    conv_w<<<64, 256, 0, stream>>>(W, Wf, out);
    qloss_kernel<<<GRID, NTHR, 0, stream>>>(emb, Wf, bias, didx, dmsk, out);
}